// Round 14
// baseline (238.337 us; speedup 1.0000x reference)
//
#include <hip/hip_runtime.h>

#define NS 65536      // stocks
#define HID 512       // hidden
#define NE 128        // industries
#define NEG 0.01f     // LeakyReLU slope

typedef int   vi4 __attribute__((ext_vector_type(4)));
typedef float vf4 __attribute__((ext_vector_type(4)));
typedef unsigned char uchar;

// ---------------------------------------------------------------------------
// K1: decode one-hot rows -> ind8[s] (byte) + per-block histogram -> bhist.
__global__ __launch_bounds__(1024) void k_find(const int* __restrict__ im,
                                               uchar* __restrict__ ind8,
                                               int* __restrict__ bhist) {
    __shared__ int lind[256];
    __shared__ int lhist[NE];
    const int b = blockIdx.x, t = threadIdx.x;
    if (t < NE) lhist[t] = 0;
    const vi4* p = reinterpret_cast<const vi4*>(im) + (size_t)b * 8192;
#pragma unroll
    for (int j = t; j < 8192; j += 1024) {   // 256 rows x 32 vi4
        vi4 v = __builtin_nontemporal_load(p + j);
        int s = j >> 5;
        int c = (j & 31) << 2;
        if (v[0] == 1) lind[s] = c;
        if (v[1] == 1) lind[s] = c + 1;
        if (v[2] == 1) lind[s] = c + 2;
        if (v[3] == 1) lind[s] = c + 3;
    }
    __syncthreads();
    if (t < 256) {
        int e = lind[t];
        ind8[b * 256 + t] = (uchar)e;
        atomicAdd(&lhist[e], 1);          // LDS atomic only
    }
    __syncthreads();
    if (t < NE) bhist[b * NE + t] = lhist[t];
}

// ---------------------------------------------------------------------------
// K2: sequential streaming aggregation. Block = (chunk c of 512 stocks,
// col-slice j of 128 cols). Streams a DENSE 256KB slice of e_s (sequential,
// nontemporal) and accumulates into LDS acc[128][128] via ds_add_f32.
// Lane l handles cols l and l+64 -> conflict-free banks. Writes 64KB partial.
__global__ __launch_bounds__(1024) void k_accum(const float* __restrict__ e_s,
                                                const uchar* __restrict__ ind8,
                                                float* __restrict__ partial) {
    __shared__ float acc[NE * 128];    // 64 KB
    __shared__ int indL[512];
    const int c = blockIdx.x >> 2;
    const int j = blockIdx.x & 3;
    const int t = threadIdx.x;
    for (int k = t; k < NE * 128; k += 1024) acc[k] = 0.f;
    if (t < 512) indL[t] = ind8[c * 512 + t];
    __syncthreads();
    const int g = t >> 6;              // 16 row-groups (one wave each)
    const int l = t & 63;
    const float* bp = e_s + ((size_t)c * 512) * HID + j * 128;
#pragma unroll 4
    for (int r = g; r < 512; r += 16) {
        int e = indL[r];               // wave-uniform broadcast
        float v0 = __builtin_nontemporal_load(bp + (size_t)r * HID + l);
        float v1 = __builtin_nontemporal_load(bp + (size_t)r * HID + l + 64);
        atomicAdd(&acc[e * 128 + l], v0);        // ds_add_f32, 2 lanes/bank
        atomicAdd(&acc[e * 128 + l + 64], v1);
    }
    __syncthreads();
    vf4* dst = reinterpret_cast<vf4*>(partial + (size_t)blockIdx.x * (NE * 128));
    const vf4* src = reinterpret_cast<const vf4*>(acc);
    for (int k = t; k < (NE * 128) / 4; k += 1024) dst[k] = src[k];
}

// ---------------------------------------------------------------------------
// K3: reduce 512 partials per industry + tiny GEMM + Binv/bias/LeakyReLU.
// Block e: aL[col] = sum over 128 chunks of partial[(c,j(col))][e][col&127].
__global__ __launch_bounds__(1024) void k_gemm(const float* __restrict__ partial,
                                               const int* __restrict__ bhist,
                                               const float* __restrict__ W,
                                               const float* __restrict__ bias,
                                               float* __restrict__ efrow) {
    __shared__ float aL[HID];
    __shared__ float redf[1024];
    __shared__ int cntS;
    const int e = blockIdx.x, t = threadIdx.x;
    if (t == 0) cntS = 0;
    __syncthreads();
    if (t < 256) atomicAdd(&cntS, bhist[t * NE + e]);
    if (t < 512) {
        const int jj = t >> 7, x = t & 127;
        float s = 0.f;
#pragma unroll 8
        for (int cc = 0; cc < 128; ++cc)
            s += partial[((size_t)(cc * 4 + jj)) * (NE * 128) + e * 128 + x];
        aL[jj * 128 + x] = s;
    }
    __syncthreads();
    const int jcol = t & (HID - 1);
    const int hh = t >> 9;            // K-half
    const int k0 = hh * 256;
    float acc = 0.f;
#pragma unroll 8
    for (int k = k0; k < k0 + 256; ++k)
        acc += aL[k] * W[k * HID + jcol];   // aL broadcast; W coalesced/L2
    redf[t] = acc;
    __syncthreads();
    if (t < HID) {
        int tot = cntS;
        float binv = (tot > 0) ? 1.0f / (float)tot : 0.0f;
        float v = (redf[t] + redf[t + HID]) * binv + bias[t];
        efrow[(size_t)e * HID + t] = (v >= 0.0f) ? v : NEG * v;
    }
}

// ---------------------------------------------------------------------------
// K4: stock-major output. Block owns 256 contiguous stocks; reads ind8 +
// efrow (L2-hot), writes 512 KB perfectly sequential, nontemporal.
__global__ __launch_bounds__(1024) void k_out(const float* __restrict__ efrow,
                                              const uchar* __restrict__ ind8,
                                              float* __restrict__ out) {
    __shared__ int lindL[256];
    const int b = blockIdx.x, t = threadIdx.x;
    if (t < 256) lindL[t] = ind8[b * 256 + t];
    __syncthreads();
    const int g = t >> 7;        // 8 groups: one stock-row per group per iter
    const int l = t & 127;       // vf4 lane within row
    vf4* outp = reinterpret_cast<vf4*>(out) + (size_t)b * 256 * 128;
#pragma unroll 4
    for (int ls = g; ls < 256; ls += 8) {
        int e = lindL[ls];       // wave-uniform broadcast
        vf4 v = reinterpret_cast<const vf4*>(efrow + (size_t)e * HID)[l];
        __builtin_nontemporal_store(v, outp + ls * 128 + l);
    }
}

extern "C" void kernel_launch(void* const* d_in, const int* in_sizes, int n_in,
                              void* d_out, int out_size, void* d_ws, size_t ws_size,
                              hipStream_t stream) {
    const float* e_s  = (const float*)d_in[0];
    const int*   im   = (const int*)d_in[1];
    const float* W    = (const float*)d_in[2];
    const float* bias = (const float*)d_in[3];
    float* out = (float*)d_out;

    char* ws = (char*)d_ws;
    // layout: ind8 64KB @0 | bhist 128KB @64K | efrow 256KB @192K
    //         | partial 32MB @512K   (total ~33 MB)
    uchar* ind8    = (uchar*)(ws + 0);
    int*   bhist   = (int*)(ws + 65536);
    float* efrow   = (float*)(ws + 196608);
    float* partial = (float*)(ws + 524288);

    k_find <<<256, 1024, 0, stream>>>(im, ind8, bhist);
    k_accum<<<512, 1024, 0, stream>>>(e_s, ind8, partial);
    k_gemm <<<NE, 1024, 0, stream>>>(partial, bhist, W, bias, efrow);
    k_out  <<<256, 1024, 0, stream>>>(efrow, ind8, out);
}

// Round 15
// 78.204 us; speedup vs baseline: 3.0476x; 3.0476x over previous
//
#include <hip/hip_runtime.h>

#define NS 65536      // stocks
#define HID 512       // hidden
#define NE 128        // industries
#define PC 8          // chunks per industry in aggregation
#define NEG 0.01f     // LeakyReLU slope

typedef int   vi4 __attribute__((ext_vector_type(4)));
typedef float vf4 __attribute__((ext_vector_type(4)));

// ---------------------------------------------------------------------------
// K1: decode one-hot rows -> ind[s]. Nontemporal vi4 loads (single-use, 33.5 MB).
__global__ __launch_bounds__(1024) void k_find(const int* __restrict__ im,
                                               int* __restrict__ ind) {
    __shared__ int lind[256];
    const int b = blockIdx.x, t = threadIdx.x;
    const vi4* p = reinterpret_cast<const vi4*>(im) + (size_t)b * 8192;
#pragma unroll
    for (int j = t; j < 8192; j += 1024) {   // 256 rows x 32 vi4, 8 iters
        vi4 v = __builtin_nontemporal_load(p + j);
        int s = j >> 5;          // local row
        int c = (j & 31) << 2;   // column of v[0]
        if (v[0] == 1) lind[s] = c;
        if (v[1] == 1) lind[s] = c + 1;
        if (v[2] == 1) lind[s] = c + 2;
        if (v[3] == 1) lind[s] = c + 3;
    }
    __syncthreads();
    if (t < 256) ind[b * 256 + t] = lind[t];
}

// ---------------------------------------------------------------------------
// K2: per-industry row-sum with self-compaction. Block = (industry e, eighth q).
// 1024 blocks x 512 threads -> 4 blocks/CU, 4x the independent gather streams
// of round 13. Scan 8192 ind entries (L2), compact ~64 matches into LDS,
// gather-sum their 2KB e_s rows (vf4, unroll 8). Writes disjoint
// partial[q][e][:] + counts[q][e]. No global atomics.
__global__ __launch_bounds__(512) void k_agg(const float* __restrict__ e_s,
                                             const int* __restrict__ ind,
                                             float* __restrict__ partial,
                                             int* __restrict__ counts) {
    __shared__ int rows[512];
    __shared__ vf4 red[512];
    __shared__ int cntL;
    const int e = blockIdx.x >> 3;
    const int q = blockIdx.x & 7;
    const int t = threadIdx.x;
    if (t == 0) cntL = 0;
    __syncthreads();
    const int base = q * (NS / PC);
#pragma unroll
    for (int k = 0; k < (NS / PC) / 512; ++k) {   // 16 coalesced L2 reads
        int idx = base + k * 512 + t;
        if (ind[idx] == e) {
            int p = atomicAdd(&cntL, 1);          // LDS atomic append
            if (p < 512) rows[p] = idx;
        }
    }
    __syncthreads();
    const int cnt = (cntL < 512) ? cntL : 512;    // ~64 expected
    const int g = t >> 7;        // 4 row-groups of 128 threads
    const int l = t & 127;       // vf4 column
    vf4 acc = {0.f, 0.f, 0.f, 0.f};
#pragma unroll 8
    for (int i = g; i < cnt; i += 4) {
        int row = rows[i];       // group-uniform broadcast
        vf4 v = __builtin_nontemporal_load(
            reinterpret_cast<const vf4*>(e_s + (size_t)row * HID) + l);
        acc += v;
    }
    red[t] = acc;
    __syncthreads();
    if (g == 0) {
        vf4 a = red[l];
#pragma unroll
        for (int p = 1; p < 4; ++p) a += red[l + p * 128];
        reinterpret_cast<vf4*>(partial + ((size_t)(q * NE + e)) * HID)[l] = a;
    }
    if (t == 0) counts[q * NE + e] = cnt;
}

// ---------------------------------------------------------------------------
// K3: finish the edge rows: efrow[e] = LeakyReLU(Binv * (sum_q partial_q[e]) @ W
// + bias). One block per industry. efrow overlays partial's q=0 plane: block e
// reads its own partial rows before writing efrow[e] (disjoint across blocks).
__global__ __launch_bounds__(1024) void k_gemm(const float* __restrict__ partial,
                                               const float* __restrict__ W,
                                               const float* __restrict__ bias,
                                               const int* __restrict__ counts,
                                               float* __restrict__ efrow) {
    __shared__ float aL[HID];
    __shared__ float redf[1024];
    const int e = blockIdx.x;
    const int t = threadIdx.x;
    if (t < HID) {
        float s = 0.f;
#pragma unroll
        for (int q = 0; q < PC; ++q) s += partial[((size_t)(q * NE + e)) * HID + t];
        aL[t] = s;
    }
    __syncthreads();
    const int j  = t & (HID - 1);
    const int hh = t >> 9;            // K-half: 0 or 1
    const int k0 = hh * 256;
    float acc = 0.f;
#pragma unroll 8
    for (int k = k0; k < k0 + 256; ++k)
        acc += aL[k] * W[k * HID + j];   // aL: LDS broadcast; W: coalesced/L2
    redf[t] = acc;
    __syncthreads();
    if (t < HID) {
        int tot = 0;
#pragma unroll
        for (int q = 0; q < PC; ++q) tot += counts[q * NE + e];
        float binv = (tot > 0) ? 1.0f / (float)tot : 0.0f;
        float v = (redf[t] + redf[t + HID]) * binv + bias[t];
        efrow[(size_t)e * HID + t] = (v >= 0.0f) ? v : NEG * v;
    }
}

// ---------------------------------------------------------------------------
// K4: stock-major output. Block owns 256 CONTIGUOUS stocks: reads ind chunk
// (L2) + efrow rows (L2-hot, 256 KB), writes 512 KB perfectly sequential
// with nontemporal stores.
__global__ __launch_bounds__(1024) void k_out(const float* __restrict__ efrow,
                                              const int* __restrict__ ind,
                                              float* __restrict__ out) {
    __shared__ int lindL[256];
    const int b = blockIdx.x, t = threadIdx.x;
    if (t < 256) lindL[t] = ind[b * 256 + t];
    __syncthreads();
    const int g = t >> 7;        // 8 groups: one stock-row per group per iter
    const int l = t & 127;       // vf4 lane within row
    vf4* outp = reinterpret_cast<vf4*>(out) + (size_t)b * 256 * 128;
#pragma unroll 4
    for (int ls = g; ls < 256; ls += 8) {
        int e = lindL[ls];       // wave-uniform broadcast
        vf4 v = reinterpret_cast<const vf4*>(efrow + (size_t)e * HID)[l];
        __builtin_nontemporal_store(v, outp + ls * 128 + l);
    }
}

extern "C" void kernel_launch(void* const* d_in, const int* in_sizes, int n_in,
                              void* d_out, int out_size, void* d_ws, size_t ws_size,
                              hipStream_t stream) {
    const float* e_s  = (const float*)d_in[0];
    const int*   im   = (const int*)d_in[1];
    const float* W    = (const float*)d_in[2];
    const float* bias = (const float*)d_in[3];
    float* out = (float*)d_out;

    char* ws = (char*)d_ws;
    // layout: ind 256KB @0 | partial 2MB @256K (efrow overlays q=0 plane)
    //         | counts 4KB @2.25MB
    int*   ind     = (int*)(ws + 0);
    float* partial = (float*)(ws + 262144);
    float* efrow   = (float*)(ws + 262144);   // overlay, safe per k_gemm
    int*   counts  = (int*)(ws + 2359296);

    k_find<<<256, 1024, 0, stream>>>(im, ind);
    k_agg <<<NE * PC, 512, 0, stream>>>(e_s, ind, partial, counts);
    k_gemm<<<NE, 1024, 0, stream>>>(partial, W, bias, counts, efrow);
    k_out <<<256, 1024, 0, stream>>>(efrow, ind, out);
}